// Round 7
// baseline (260.950 us; speedup 1.0000x reference)
//
#include <hip/hip_runtime.h>
#include <hip/hip_bf16.h>

#define DIN 4096
#define DOUT 4096
#define NROWS 8192  // B*S = 4*2048

typedef int i32x4 __attribute__((ext_vector_type(4)));
typedef int i32x16 __attribute__((ext_vector_type(16)));

// ---------------- block-level absmax reduce (4 waves, 256 threads) -------------
__device__ __forceinline__ float block_absmax(float m, float* red) {
  #pragma unroll
  for (int off = 32; off > 0; off >>= 1)
    m = fmaxf(m, __shfl_down(m, off));
  const int tid = threadIdx.x;
  if ((tid & 63) == 0) red[tid >> 6] = m;
  __syncthreads();
  return fmaxf(fmaxf(red[0], red[1]), fmaxf(red[2], red[3]));
}

// ---------------- kernel 1: fused FWHT+quant (rows) / weight quant (rows) ------
// blocks [0,8192): FWHT radix-16 (bit-exact reference op tree) + 8b per-token
// quant; blocks [8192,12288): per-channel 4b weight quant. One launch.
__global__ __launch_bounds__(256) void fused_quant_kernel(
    const float* __restrict__ in, const float* __restrict__ w,
    char* __restrict__ qx, char* __restrict__ qw,
    float* __restrict__ sx, float* __restrict__ sw) {
  __shared__ float lds[4352];  // fwht: 4096+pad; wquant: reuses first 4096
  __shared__ float red[4];
  const int tid = threadIdx.x;

  if (blockIdx.x < NROWS) {
    const size_t row = blockIdx.x;
    const int th = tid >> 4, tl = tid & 15;
    float v[16];
    const float4* src = (const float4*)(in + row * DIN);
    #pragma unroll
    for (int k = 0; k < 4; ++k) {
      float4 f = src[tid * 4 + k];
      v[4 * k + 0] = f.x; v[4 * k + 1] = f.y;
      v[4 * k + 2] = f.z; v[4 * k + 3] = f.w;
    }
    #pragma unroll
    for (int hb = 1; hb < 16; hb <<= 1)
      #pragma unroll
      for (int j = 0; j < 16; ++j)
        if (!(j & hb)) {
          float a0 = v[j], b0 = v[j | hb];
          v[j] = a0 + b0; v[j | hb] = a0 - b0;
        }
    #pragma unroll
    for (int j = 0; j < 16; ++j) lds[17 * tid + j] = v[j];
    __syncthreads();
    #pragma unroll
    for (int j = 0; j < 16; ++j) v[j] = lds[272 * th + 17 * j + tl];
    #pragma unroll
    for (int hb = 1; hb < 16; hb <<= 1)
      #pragma unroll
      for (int j = 0; j < 16; ++j)
        if (!(j & hb)) {
          float a0 = v[j], b0 = v[j | hb];
          v[j] = a0 + b0; v[j | hb] = a0 - b0;
        }
    #pragma unroll
    for (int j = 0; j < 16; ++j) lds[272 * th + 17 * j + tl] = v[j];
    __syncthreads();
    #pragma unroll
    for (int j = 0; j < 16; ++j) v[j] = lds[272 * j + 17 * th + tl];
    #pragma unroll
    for (int hb = 1; hb < 16; hb <<= 1)
      #pragma unroll
      for (int j = 0; j < 16; ++j)
        if (!(j & hb)) {
          float a0 = v[j], b0 = v[j | hb];
          v[j] = a0 + b0; v[j | hb] = a0 - b0;
        }
    float m = 0.0f;
    #pragma unroll
    for (int j = 0; j < 16; ++j) m = fmaxf(m, fabsf(v[j]));
    #pragma unroll
    for (int j = 0; j < 16; ++j) lds[272 * j + 17 * th + tl] = v[j];
    float mx = block_absmax(m, red) * 0.015625f;  // 1/sqrt(4096) exact
    float scale = fmaxf(mx / 127.0f, 1e-8f);
    if (tid == 0) sx[row] = scale;
    const float rs = 1.0f / scale;
    char pk[16];
    #pragma unroll
    for (int j = 0; j < 16; ++j) {
      float q = fminf(fmaxf(rintf((lds[17 * tid + j] * 0.015625f) * rs), -127.f),
                      127.f);
      pk[j] = (char)q;
    }
    *(int4*)(qx + row * DIN + (size_t)tid * 16) = *(const int4*)pk;
  } else {
    const size_t row = blockIdx.x - NROWS;
    const float4* src = (const float4*)(w + row * DIN);
    float4* b4 = (float4*)lds;
    float m = 0.0f;
    for (int i = tid; i < DIN / 4; i += 256) {
      float4 v = src[i];
      b4[i] = v;
      m = fmaxf(m, fmaxf(fmaxf(fabsf(v.x), fabsf(v.y)),
                         fmaxf(fabsf(v.z), fabsf(v.w))));
    }
    float mx = block_absmax(m, red);  // internal barrier covers lds writes
    float scale = fmaxf(mx / 7.0f, 1e-8f);
    if (tid == 0) sw[row] = scale;
    char* dst = qw + row * DIN;
    const float rs = 1.0f / scale;
    for (int i0 = tid * 4; i0 < DIN; i0 += 1024) {
      char4 pk;
      float q0 = fminf(fmaxf(rintf(lds[i0 + 0] * rs), -7.f), 7.f);
      float q1 = fminf(fmaxf(rintf(lds[i0 + 1] * rs), -7.f), 7.f);
      float q2 = fminf(fmaxf(rintf(lds[i0 + 2] * rs), -7.f), 7.f);
      float q3 = fminf(fmaxf(rintf(lds[i0 + 3] * rs), -7.f), 7.f);
      pk.x = (char)q0; pk.y = (char)q1; pk.z = (char)q2; pk.w = (char)q3;
      *(char4*)(dst + i0) = pk;
    }
  }
}

// ---------------- kernel 3: i8 MFMA GEMM, 256x256, 8-phase + fa prefetch -------
// R4's proven two-barrier skeleton (reads+stages | BAR | wait | MFMA | BAR) with
// fa fragments prefetched ONE PHASE EARLY: MFMA waits on last phase's reads
// (counted lgkmcnt(4)) which landed during the previous MFMA window -> the
// exposed lgkmcnt(0) drain is removed. MFMA 32x32x32 (swapped -> C^T frags,
// HW-verified in R5). vmcnt moved to ph3/ph7-end (buf complete before the
// ph4/ph8 prefetch that reads it). Stage slots identical to R2/R4 ledger.
__global__ __launch_bounds__(512, 2) void gemm_kernel(
    const char* __restrict__ A,   // [NROWS][DIN] q_x int8
    const char* __restrict__ Bt,  // [DOUT][DIN]  q_w int8
    const float* __restrict__ sx, const float* __restrict__ sw,
    const float* __restrict__ bias, float* __restrict__ out) {
  __shared__ char lds[131072];
  const int tid = threadIdx.x;
  const int lane = tid & 63;
  const int wid = tid >> 6;
  const int wr = wid >> 2;   // 0..1
  const int wc = wid & 3;    // 0..3
  const int lh = lane >> 5;  // k-half within fragment
  const int l31 = lane & 31;
  int bid = blockIdx.x;                    // 512 blocks
  int swz = (bid & 7) * 64 + (bid >> 3);   // bijective XCD swizzle (512%8==0)
  const size_t row0 = (size_t)(swz >> 4) * 256;
  const size_t col0 = (size_t)(swz & 15) * 256;

  i32x16 acc[4][2] = {};  // [slab q][nn] C^T fragments
  i32x4 faA[4], faB[4];   // [kk] double-buffered A frags (prefetch 1 phase)
  i32x4 fb[2][4];         // [nn][kk] B frags (per K-tile)

#define STAGE(MAT, GROW0, KT, LBASE)                                          \
  {                                                                           \
    _Pragma("unroll")                                                         \
    for (int j = 0; j < 2; ++j) {                                             \
      int chunk = j * 8 + wid;                                                \
      int rr = chunk * 8 + (lane >> 3);                                       \
      int cc = (KT) * 128 + (((lane & 7) ^ (lane >> 3)) << 4);                \
      const char* src = (MAT) + ((GROW0) + rr) * (size_t)DIN + cc;            \
      __builtin_amdgcn_global_load_lds(                                       \
          (const __attribute__((address_space(1))) void*)src,                 \
          (__attribute__((address_space(3))) void*)(lds + (LBASE) +           \
                                                    chunk * 1024),            \
          16, 0, 0);                                                          \
    }                                                                         \
  }
#define STAGE_A(P, HALF, KT) \
  STAGE(A, row0 + (HALF) * 128, KT, (P) * 32768 + (HALF) * 16384)
#define STAGE_B(P, HALF, KT) \
  STAGE(Bt, col0 + (HALF) * 128, KT, 65536 + (P) * 32768 + (HALF) * 16384)

#define DS_FA(DST, Q, P)                                                      \
  {                                                                           \
    int ar_ = (Q) * 64 + wr * 32 + l31;                                       \
    _Pragma("unroll")                                                         \
    for (int kk = 0; kk < 4; ++kk)                                            \
      DST[kk] = *(const i32x4*)(lds + (P) * 32768 + ar_ * 128 +               \
                                (((kk * 2 + lh) ^ (ar_ & 7)) << 4));          \
  }
#define DS_FB(P)                                                              \
  {                                                                           \
    _Pragma("unroll")                                                         \
    for (int nn = 0; nn < 2; ++nn) {                                          \
      int br_ = wc * 64 + nn * 32 + l31;                                      \
      _Pragma("unroll")                                                       \
      for (int kk = 0; kk < 4; ++kk)                                          \
        fb[nn][kk] = *(const i32x4*)(lds + 65536 + (P) * 32768 + br_ * 128 +  \
                                     (((kk * 2 + lh) ^ (br_ & 7)) << 4));     \
    }                                                                         \
  }
#define MFMA8(Q, FA)                                                          \
  {                                                                           \
    __builtin_amdgcn_s_setprio(1);                                            \
    _Pragma("unroll")                                                         \
    for (int kk = 0; kk < 4; ++kk)                                            \
      _Pragma("unroll")                                                       \
      for (int nn = 0; nn < 2; ++nn)                                          \
        acc[Q][nn] = __builtin_amdgcn_mfma_i32_32x32x32_i8(                   \
            fb[nn][kk], FA[kk], acc[Q][nn], 0, 0, 0);                         \
    __builtin_amdgcn_s_setprio(0);                                            \
  }
#define BAR() __builtin_amdgcn_s_barrier()
#define WAIT_LGKM4() \
  { asm volatile("s_waitcnt lgkmcnt(4)" ::: "memory"); __builtin_amdgcn_sched_barrier(0); }
#define WAIT_LGKM0() \
  { asm volatile("s_waitcnt lgkmcnt(0)" ::: "memory"); __builtin_amdgcn_sched_barrier(0); }

  // -------- prologue: kt0 -> buf0 (4 half-tiles), kt1 -> buf1 (3 half-tiles)
  STAGE_B(0, 0, 0); STAGE_B(0, 1, 0); STAGE_A(0, 0, 0); STAGE_A(0, 1, 0);
  STAGE_B(1, 0, 1); STAGE_B(1, 1, 1); STAGE_A(1, 0, 1);
  asm volatile("s_waitcnt vmcnt(6)" ::: "memory");  // buf0 fully landed
  BAR();
  DS_FA(faA, 0, 0);  // prime slab0

  #pragma unroll 1
  for (int i = 0; i < 16; ++i) {
    const int a = 2 * i, b = 2 * i + 1;
    const bool nl = (i < 15);
    // ---- ph1: fb(buf0) + prefetch slab1; stage A11(b); MFMA slab0 (primed)
    DS_FB(0);
    DS_FA(faB, 1, 0);
    STAGE_A(1, 1, b);
    asm volatile("s_waitcnt lgkmcnt(8)" ::: "memory");
    BAR(); WAIT_LGKM4();
    MFMA8(0, faA);
    BAR();
    // ---- ph2: prefetch slab2; stage B00(a+2); MFMA slab1
    DS_FA(faA, 2, 0);
    if (nl) STAGE_B(0, 0, a + 2);
    BAR(); WAIT_LGKM4();
    MFMA8(1, faB);
    BAR();
    // ---- ph3: prefetch slab3; stage B01(a+2); MFMA slab2; vmcnt->buf1 ready
    DS_FA(faB, 3, 0);
    if (nl) STAGE_B(0, 1, a + 2);
    BAR(); WAIT_LGKM4();
    MFMA8(2, faA);
    if (nl) { asm volatile("s_waitcnt vmcnt(4)" ::: "memory"); }
    else    { asm volatile("s_waitcnt vmcnt(0)" ::: "memory"); }
    BAR();
    // ---- ph4: prefetch slab0 of buf1; stage A00(a+2); MFMA slab3
    DS_FA(faA, 0, 1);
    if (nl) STAGE_A(0, 0, a + 2);
    BAR(); WAIT_LGKM4();
    MFMA8(3, faB);
    BAR();
    // ---- ph5: fb(buf1) + prefetch slab1; stage A01(a+2); MFMA slab0
    DS_FB(1);
    DS_FA(faB, 1, 1);
    if (nl) STAGE_A(0, 1, a + 2);
    asm volatile("s_waitcnt lgkmcnt(8)" ::: "memory");
    BAR(); WAIT_LGKM4();
    MFMA8(0, faA);
    BAR();
    // ---- ph6: prefetch slab2; stage B10(b+2); MFMA slab1
    DS_FA(faA, 2, 1);
    if (nl) STAGE_B(1, 0, b + 2);
    BAR(); WAIT_LGKM4();
    MFMA8(1, faB);
    BAR();
    // ---- ph7: prefetch slab3; stage B11(b+2); MFMA slab2; vmcnt->buf0 ready
    DS_FA(faB, 3, 1);
    if (nl) STAGE_B(1, 1, b + 2);
    BAR(); WAIT_LGKM4();
    MFMA8(2, faA);
    if (nl) { asm volatile("s_waitcnt vmcnt(4)" ::: "memory"); }
    BAR();
    // ---- ph8: prefetch slab0 of next buf0; stage A10(b+2); MFMA slab3
    if (nl) { DS_FA(faA, 0, 0); STAGE_A(1, 0, b + 2); }
    BAR();
    if (nl) { WAIT_LGKM4(); } else { WAIT_LGKM0(); }
    MFMA8(3, faB);
    BAR();
  }

  // -------- epilogue (C^T frags, HW-verified R5): gr = base+(lane&31);
  // gc = cbase + 8*(reg>>2) + 4*lh + (reg&3) => float4 stores.
  #pragma unroll
  for (int q = 0; q < 4; ++q) {
    size_t gr = row0 + q * 64 + wr * 32 + l31;
    float sxr = sx[gr];
    float* orow = out + gr * DOUT;
    #pragma unroll
    for (int nn = 0; nn < 2; ++nn) {
      #pragma unroll
      for (int r4 = 0; r4 < 4; ++r4) {
        size_t gc0 = col0 + wc * 64 + nn * 32 + 8 * r4 + 4 * lh;
        float4 swv = *(const float4*)(sw + gc0);
        float4 bv = *(const float4*)(bias + gc0);
        float4 o;
        o.x = (float)acc[q][nn][r4 * 4 + 0] * (sxr * swv.x) + bv.x;
        o.y = (float)acc[q][nn][r4 * 4 + 1] * (sxr * swv.y) + bv.y;
        o.z = (float)acc[q][nn][r4 * 4 + 2] * (sxr * swv.z) + bv.z;
        o.w = (float)acc[q][nn][r4 * 4 + 3] * (sxr * swv.w) + bv.w;
        *(float4*)(orow + gc0) = o;
      }
    }
  }
#undef STAGE
#undef STAGE_A
#undef STAGE_B
#undef DS_FA
#undef DS_FB
#undef MFMA8
#undef BAR
#undef WAIT_LGKM4
#undef WAIT_LGKM0
}

// ---------------- kernel 4: per-token 8-bit fake quant of output, in place ----
__global__ __launch_bounds__(256) void rowquant_kernel(float* __restrict__ out) {
  __shared__ float red[4];
  const int tid = threadIdx.x;
  const size_t row = blockIdx.x;
  float4* g4 = (float4*)(out + row * DOUT);
  float4 v[4];
  float m = 0.0f;
  #pragma unroll
  for (int k = 0; k < 4; ++k) {
    v[k] = g4[tid + k * 256];
    m = fmaxf(m, fmaxf(fmaxf(fabsf(v[k].x), fabsf(v[k].y)),
                       fmaxf(fabsf(v[k].z), fabsf(v[k].w))));
  }
  float mx = block_absmax(m, red);
  float scale = fmaxf(mx / 127.0f, 1e-8f);
  #pragma unroll
  for (int k = 0; k < 4; ++k) {
    float4 w = v[k];
    w.x = fminf(fmaxf(rintf(w.x / scale), -127.0f), 127.0f) * scale;
    w.y = fminf(fmaxf(rintf(w.y / scale), -127.0f), 127.0f) * scale;
    w.z = fminf(fmaxf(rintf(w.z / scale), -127.0f), 127.0f) * scale;
    w.w = fminf(fmaxf(rintf(w.w / scale), -127.0f), 127.0f) * scale;
    g4[tid + k * 256] = w;
  }
}

extern "C" void kernel_launch(void* const* d_in, const int* in_sizes, int n_in,
                              void* d_out, int out_size, void* d_ws, size_t ws_size,
                              hipStream_t stream) {
  (void)in_sizes; (void)n_in; (void)out_size; (void)ws_size;
  const float* input = (const float*)d_in[0];
  const float* weight = (const float*)d_in[1];
  const float* bias = (const float*)d_in[2];
  float* out = (float*)d_out;
  char* ws = (char*)d_ws;
  char* qx = ws;
  char* qw = ws + ((size_t)32 << 20);
  float* sx = (float*)(ws + ((size_t)48 << 20));
  float* sw = (float*)(ws + ((size_t)48 << 20) + ((size_t)32 << 10));

  fused_quant_kernel<<<NROWS + DOUT, 256, 0, stream>>>(input, weight, qx, qw,
                                                       sx, sw);
  gemm_kernel<<<512, 512, 0, stream>>>(qx, qw, sx, sw, bias, out);
  rowquant_kernel<<<NROWS, 256, 0, stream>>>(out);
}

// Round 8
// 230.067 us; speedup vs baseline: 1.1342x; 1.1342x over previous
//
#include <hip/hip_runtime.h>
#include <hip/hip_bf16.h>

#define DIN 4096
#define DOUT 4096
#define NROWS 8192  // B*S = 4*2048

typedef int i32x4 __attribute__((ext_vector_type(4)));

// ---------------- block-level absmax reduce (4 waves, 256 threads) -------------
__device__ __forceinline__ float block_absmax(float m, float* red) {
  #pragma unroll
  for (int off = 32; off > 0; off >>= 1)
    m = fmaxf(m, __shfl_down(m, off));
  const int tid = threadIdx.x;
  if ((tid & 63) == 0) red[tid >> 6] = m;
  __syncthreads();
  return fmaxf(fmaxf(red[0], red[1]), fmaxf(red[2], red[3]));
}

// ---------------- kernel 1: fused FWHT+quant (rows) / weight quant (rows) ------
__global__ __launch_bounds__(256) void fused_quant_kernel(
    const float* __restrict__ in, const float* __restrict__ w,
    char* __restrict__ qx, char* __restrict__ qw,
    float* __restrict__ sx, float* __restrict__ sw) {
  __shared__ float lds[4352];
  __shared__ float red[4];
  const int tid = threadIdx.x;

  if (blockIdx.x < NROWS) {
    const size_t row = blockIdx.x;
    const int th = tid >> 4, tl = tid & 15;
    float v[16];
    const float4* src = (const float4*)(in + row * DIN);
    #pragma unroll
    for (int k = 0; k < 4; ++k) {
      float4 f = src[tid * 4 + k];
      v[4 * k + 0] = f.x; v[4 * k + 1] = f.y;
      v[4 * k + 2] = f.z; v[4 * k + 3] = f.w;
    }
    #pragma unroll
    for (int hb = 1; hb < 16; hb <<= 1)
      #pragma unroll
      for (int j = 0; j < 16; ++j)
        if (!(j & hb)) {
          float a0 = v[j], b0 = v[j | hb];
          v[j] = a0 + b0; v[j | hb] = a0 - b0;
        }
    #pragma unroll
    for (int j = 0; j < 16; ++j) lds[17 * tid + j] = v[j];
    __syncthreads();
    #pragma unroll
    for (int j = 0; j < 16; ++j) v[j] = lds[272 * th + 17 * j + tl];
    #pragma unroll
    for (int hb = 1; hb < 16; hb <<= 1)
      #pragma unroll
      for (int j = 0; j < 16; ++j)
        if (!(j & hb)) {
          float a0 = v[j], b0 = v[j | hb];
          v[j] = a0 + b0; v[j | hb] = a0 - b0;
        }
    #pragma unroll
    for (int j = 0; j < 16; ++j) lds[272 * th + 17 * j + tl] = v[j];
    __syncthreads();
    #pragma unroll
    for (int j = 0; j < 16; ++j) v[j] = lds[272 * j + 17 * th + tl];
    #pragma unroll
    for (int hb = 1; hb < 16; hb <<= 1)
      #pragma unroll
      for (int j = 0; j < 16; ++j)
        if (!(j & hb)) {
          float a0 = v[j], b0 = v[j | hb];
          v[j] = a0 + b0; v[j | hb] = a0 - b0;
        }
    float m = 0.0f;
    #pragma unroll
    for (int j = 0; j < 16; ++j) m = fmaxf(m, fabsf(v[j]));
    #pragma unroll
    for (int j = 0; j < 16; ++j) lds[272 * j + 17 * th + tl] = v[j];
    float mx = block_absmax(m, red) * 0.015625f;  // 1/sqrt(4096) exact
    float scale = fmaxf(mx / 127.0f, 1e-8f);
    if (tid == 0) sx[row] = scale;
    const float rs = 1.0f / scale;
    char pk[16];
    #pragma unroll
    for (int j = 0; j < 16; ++j) {
      float q = fminf(fmaxf(rintf((lds[17 * tid + j] * 0.015625f) * rs), -127.f),
                      127.f);
      pk[j] = (char)q;
    }
    *(int4*)(qx + row * DIN + (size_t)tid * 16) = *(const int4*)pk;
  } else {
    const size_t row = blockIdx.x - NROWS;
    const float4* src = (const float4*)(w + row * DIN);
    float4* b4 = (float4*)lds;
    float m = 0.0f;
    for (int i = tid; i < DIN / 4; i += 256) {
      float4 v = src[i];
      b4[i] = v;
      m = fmaxf(m, fmaxf(fmaxf(fabsf(v.x), fabsf(v.y)),
                         fmaxf(fabsf(v.z), fabsf(v.w))));
    }
    float mx = block_absmax(m, red);
    float scale = fmaxf(mx / 7.0f, 1e-8f);
    if (tid == 0) sw[row] = scale;
    char* dst = qw + row * DIN;
    const float rs = 1.0f / scale;
    for (int i0 = tid * 4; i0 < DIN; i0 += 1024) {
      char4 pk;
      float q0 = fminf(fmaxf(rintf(lds[i0 + 0] * rs), -7.f), 7.f);
      float q1 = fminf(fmaxf(rintf(lds[i0 + 1] * rs), -7.f), 7.f);
      float q2 = fminf(fmaxf(rintf(lds[i0 + 2] * rs), -7.f), 7.f);
      float q3 = fminf(fmaxf(rintf(lds[i0 + 3] * rs), -7.f), 7.f);
      pk.x = (char)q0; pk.y = (char)q1; pk.z = (char)q2; pk.w = (char)q3;
      *(char4*)(dst + i0) = pk;
    }
  }
}

// ---------------- kernel 3: i8 MFMA GEMM, 256x256, 8-phase, fa prefetch --------
// R4-EXACT 16x16x64 path (0 conflicts, verified C^T epilogue) + the one
// isolated change: A-fragments ds_read ONE PHASE EARLY into faA/faB, MFMA
// waits counted lgkmcnt(4) instead of lgkmcnt(0). vmcnt(4) at ph3/ph7-end
// (buffer complete before the ph4/ph8 prefetch that reads it). Stage slots
// and swizzle identical to the R2/R4 proven ledger.
__global__ __launch_bounds__(512, 2) void gemm_kernel(
    const char* __restrict__ A,   // [NROWS][DIN] q_x int8
    const char* __restrict__ Bt,  // [DOUT][DIN]  q_w int8
    const float* __restrict__ sx, const float* __restrict__ sw,
    const float* __restrict__ bias, float* __restrict__ out) {
  __shared__ char lds[131072];
  const int tid = threadIdx.x;
  const int lane = tid & 63;
  const int wid = tid >> 6;
  const int wr = wid >> 2;  // 0..1
  const int wc = wid & 3;   // 0..3
  int bid = blockIdx.x;                    // 512 blocks
  int swz = (bid & 7) * 64 + (bid >> 3);   // bijective XCD swizzle (512%8==0)
  const size_t row0 = (size_t)(swz >> 4) * 256;
  const size_t col0 = (size_t)(swz & 15) * 256;
  const int slot0 = (((lane >> 4) ^ (lane & 7)) << 4);  // swizzled 16B slot

  i32x4 acc[4][2][4] = {};   // [slab q][mm][nn] — C^T fragments
  i32x4 fb[4][2];            // [nn][kk]
  i32x4 faA[2][2], faB[2][2];  // [mm][kk] — double-buffered prefetch

#define STAGE(MAT, GROW0, KT, LBASE)                                          \
  {                                                                           \
    _Pragma("unroll")                                                         \
    for (int j = 0; j < 2; ++j) {                                             \
      int chunk = j * 8 + wid;                                                \
      int rr = chunk * 8 + (lane >> 3);                                       \
      int cc = (KT) * 128 + (((lane & 7) ^ (lane >> 3)) << 4);                \
      const char* src = (MAT) + ((GROW0) + rr) * (size_t)DIN + cc;            \
      __builtin_amdgcn_global_load_lds(                                       \
          (const __attribute__((address_space(1))) void*)src,                 \
          (__attribute__((address_space(3))) void*)(lds + (LBASE) +           \
                                                    chunk * 1024),            \
          16, 0, 0);                                                          \
    }                                                                         \
  }
#define STAGE_A(P, HALF, KT) \
  STAGE(A, row0 + (HALF) * 128, KT, (P) * 32768 + (HALF) * 16384)
#define STAGE_B(P, HALF, KT) \
  STAGE(Bt, col0 + (HALF) * 128, KT, 65536 + (P) * 32768 + (HALF) * 16384)

#define DS_FA(DST, Q, P)                                                      \
  {                                                                           \
    _Pragma("unroll")                                                         \
    for (int mm = 0; mm < 2; ++mm) {                                          \
      int ar = (Q) * 64 + wr * 32 + mm * 16 + (lane & 15);                    \
      _Pragma("unroll")                                                       \
      for (int kk = 0; kk < 2; ++kk)                                          \
        DST[mm][kk] =                                                         \
            *(const i32x4*)(lds + (P) * 32768 + ar * 128 + (slot0 ^ (kk * 64))); \
    }                                                                         \
  }
#define DS_FB(P)                                                              \
  {                                                                           \
    _Pragma("unroll")                                                         \
    for (int nn = 0; nn < 4; ++nn) {                                          \
      int br = wc * 64 + nn * 16 + (lane & 15);                               \
      _Pragma("unroll")                                                       \
      for (int kk = 0; kk < 2; ++kk)                                          \
        fb[nn][kk] = *(const i32x4*)(lds + 65536 + (P) * 32768 + br * 128 +   \
                                     (slot0 ^ (kk * 64)));                    \
    }                                                                         \
  }
#define MFMA16(Q, FA)                                                         \
  {                                                                           \
    __builtin_amdgcn_s_setprio(1);                                            \
    _Pragma("unroll")                                                         \
    for (int kk = 0; kk < 2; ++kk)                                            \
      _Pragma("unroll")                                                       \
      for (int mm = 0; mm < 2; ++mm)                                          \
        _Pragma("unroll")                                                     \
        for (int nn = 0; nn < 4; ++nn)                                        \
          acc[Q][mm][nn] = __builtin_amdgcn_mfma_i32_16x16x64_i8(             \
              fb[nn][kk], FA[mm][kk], acc[Q][mm][nn], 0, 0, 0);               \
    __builtin_amdgcn_s_setprio(0);                                            \
  }
#define BAR() __builtin_amdgcn_s_barrier()
#define SCHED0() __builtin_amdgcn_sched_barrier(0)
#define WAIT_LGKM4() \
  { asm volatile("s_waitcnt lgkmcnt(4)" ::: "memory"); SCHED0(); }
#define WAIT_LGKM0() \
  { asm volatile("s_waitcnt lgkmcnt(0)" ::: "memory"); SCHED0(); }

  // -------- prologue: kt0 -> buf0 (4 half-tiles), kt1 -> buf1 (3 half-tiles)
  STAGE_B(0, 0, 0); STAGE_B(0, 1, 0); STAGE_A(0, 0, 0); STAGE_A(0, 1, 0);
  STAGE_B(1, 0, 1); STAGE_B(1, 1, 1); STAGE_A(1, 0, 1);
  asm volatile("s_waitcnt vmcnt(6)" ::: "memory");  // buf0 fully landed
  BAR();
  DS_FA(faA, 0, 0);  // prime slab0 of buf0

  #pragma unroll 1
  for (int i = 0; i < 16; ++i) {
    const int a = 2 * i, b = 2 * i + 1;
    const bool nl = (i < 15);
    // ---- ph1: fb(buf0); prefetch slab1->faB; stage A11(b); MFMA slab0(faA)
    DS_FB(0);
    SCHED0();  // pin fb-first issue order so lgkm(4) leaves only the prefetch
    DS_FA(faB, 1, 0);
    STAGE_A(1, 1, b);
    asm volatile("s_waitcnt lgkmcnt(8)" ::: "memory");
    BAR(); WAIT_LGKM4();
    MFMA16(0, faA);
    BAR();
    // ---- ph2: prefetch slab2->faA; stage B00(a+2); MFMA slab1(faB)
    DS_FA(faA, 2, 0);
    if (nl) STAGE_B(0, 0, a + 2);
    BAR(); WAIT_LGKM4();
    MFMA16(1, faB);
    BAR();
    // ---- ph3: prefetch slab3->faB; stage B01(a+2); MFMA slab2(faA);
    //           vmcnt -> buf1 fully landed (before ph4's buf1 prefetch)
    DS_FA(faB, 3, 0);
    if (nl) STAGE_B(0, 1, a + 2);
    BAR(); WAIT_LGKM4();
    MFMA16(2, faA);
    if (nl) { asm volatile("s_waitcnt vmcnt(4)" ::: "memory"); }
    else    { asm volatile("s_waitcnt vmcnt(0)" ::: "memory"); }
    BAR();
    // ---- ph4: prefetch buf1 slab0->faA; stage A00(a+2); MFMA slab3(faB)
    DS_FA(faA, 0, 1);
    if (nl) STAGE_A(0, 0, a + 2);
    BAR(); WAIT_LGKM4();
    MFMA16(3, faB);
    BAR();
    // ---- ph5: fb(buf1); prefetch slab1->faB; stage A01(a+2); MFMA slab0(faA)
    DS_FB(1);
    SCHED0();
    DS_FA(faB, 1, 1);
    if (nl) STAGE_A(0, 1, a + 2);
    asm volatile("s_waitcnt lgkmcnt(8)" ::: "memory");
    BAR(); WAIT_LGKM4();
    MFMA16(0, faA);
    BAR();
    // ---- ph6: prefetch slab2->faA; stage B10(b+2); MFMA slab1(faB)
    DS_FA(faA, 2, 1);
    if (nl) STAGE_B(1, 0, b + 2);
    BAR(); WAIT_LGKM4();
    MFMA16(1, faB);
    BAR();
    // ---- ph7: prefetch slab3->faB; stage B11(b+2); MFMA slab2(faA);
    //           vmcnt -> buf0(a+2) fully landed (before ph8's prime)
    DS_FA(faB, 3, 1);
    if (nl) STAGE_B(1, 1, b + 2);
    BAR(); WAIT_LGKM4();
    MFMA16(2, faA);
    if (nl) { asm volatile("s_waitcnt vmcnt(4)" ::: "memory"); }
    BAR();
    // ---- ph8: prime next buf0 slab0->faA; stage A10(b+2); MFMA slab3(faB)
    if (nl) { DS_FA(faA, 0, 0); STAGE_A(1, 0, b + 2); }
    BAR();
    if (nl) { WAIT_LGKM4(); } else { WAIT_LGKM0(); }
    MFMA16(3, faB);
    BAR();
  }

  // -------- epilogue (C^T frags, R4-verified): float4 stores
  #pragma unroll
  for (int q = 0; q < 4; ++q) {
    #pragma unroll
    for (int mm = 0; mm < 2; ++mm) {
      size_t gr = row0 + q * 64 + wr * 32 + mm * 16 + (lane & 15);
      float sxr = sx[gr];
      float* orow = out + gr * DOUT;
      #pragma unroll
      for (int nn = 0; nn < 4; ++nn) {
        size_t gc0 = col0 + wc * 64 + nn * 16 + ((lane >> 4) << 2);
        float4 swv = *(const float4*)(sw + gc0);
        float4 bv = *(const float4*)(bias + gc0);
        float4 o;
        o.x = (float)acc[q][mm][nn][0] * (sxr * swv.x) + bv.x;
        o.y = (float)acc[q][mm][nn][1] * (sxr * swv.y) + bv.y;
        o.z = (float)acc[q][mm][nn][2] * (sxr * swv.z) + bv.z;
        o.w = (float)acc[q][mm][nn][3] * (sxr * swv.w) + bv.w;
        *(float4*)(orow + gc0) = o;
      }
    }
  }
#undef STAGE
#undef STAGE_A
#undef STAGE_B
#undef DS_FA
#undef DS_FB
#undef MFMA16
#undef BAR
#undef SCHED0
#undef WAIT_LGKM4
#undef WAIT_LGKM0
}

// ---------------- kernel 4: per-token 8-bit fake quant of output, in place ----
__global__ __launch_bounds__(256) void rowquant_kernel(float* __restrict__ out) {
  __shared__ float red[4];
  const int tid = threadIdx.x;
  const size_t row = blockIdx.x;
  float4* g4 = (float4*)(out + row * DOUT);
  float4 v[4];
  float m = 0.0f;
  #pragma unroll
  for (int k = 0; k < 4; ++k) {
    v[k] = g4[tid + k * 256];
    m = fmaxf(m, fmaxf(fmaxf(fabsf(v[k].x), fabsf(v[k].y)),
                       fmaxf(fabsf(v[k].z), fabsf(v[k].w))));
  }
  float mx = block_absmax(m, red);
  float scale = fmaxf(mx / 127.0f, 1e-8f);
  #pragma unroll
  for (int k = 0; k < 4; ++k) {
    float4 w = v[k];
    w.x = fminf(fmaxf(rintf(w.x / scale), -127.0f), 127.0f) * scale;
    w.y = fminf(fmaxf(rintf(w.y / scale), -127.0f), 127.0f) * scale;
    w.z = fminf(fmaxf(rintf(w.z / scale), -127.0f), 127.0f) * scale;
    w.w = fminf(fmaxf(rintf(w.w / scale), -127.0f), 127.0f) * scale;
    g4[tid + k * 256] = w;
  }
}

extern "C" void kernel_launch(void* const* d_in, const int* in_sizes, int n_in,
                              void* d_out, int out_size, void* d_ws, size_t ws_size,
                              hipStream_t stream) {
  (void)in_sizes; (void)n_in; (void)out_size; (void)ws_size;
  const float* input = (const float*)d_in[0];
  const float* weight = (const float*)d_in[1];
  const float* bias = (const float*)d_in[2];
  float* out = (float*)d_out;
  char* ws = (char*)d_ws;
  char* qx = ws;
  char* qw = ws + ((size_t)32 << 20);
  float* sx = (float*)(ws + ((size_t)48 << 20));
  float* sw = (float*)(ws + ((size_t)48 << 20) + ((size_t)32 << 10));

  fused_quant_kernel<<<NROWS + DOUT, 256, 0, stream>>>(input, weight, qx, qw,
                                                       sx, sw);
  gemm_kernel<<<512, 512, 0, stream>>>(qx, qw, sx, sw, bias, out);
  rowquant_kernel<<<NROWS, 256, 0, stream>>>(out);
}

// Round 9
// 229.456 us; speedup vs baseline: 1.1373x; 1.0027x over previous
//
#include <hip/hip_runtime.h>
#include <hip/hip_bf16.h>

#define DIN 4096
#define DOUT 4096
#define NROWS 8192  // B*S = 4*2048

typedef int i32x4 __attribute__((ext_vector_type(4)));

// ---------------- block-level absmax reduce (4 waves, 256 threads) -------------
__device__ __forceinline__ float block_absmax(float m, float* red) {
  #pragma unroll
  for (int off = 32; off > 0; off >>= 1)
    m = fmaxf(m, __shfl_down(m, off));
  const int tid = threadIdx.x;
  if ((tid & 63) == 0) red[tid >> 6] = m;
  __syncthreads();
  return fmaxf(fmaxf(red[0], red[1]), fmaxf(red[2], red[3]));
}

// ---------------- kernel 1: fused FWHT+quant (rows) / weight quant (rows) ------
__global__ __launch_bounds__(256) void fused_quant_kernel(
    const float* __restrict__ in, const float* __restrict__ w,
    char* __restrict__ qx, char* __restrict__ qw,
    float* __restrict__ sx, float* __restrict__ sw) {
  __shared__ float lds[4352];
  __shared__ float red[4];
  const int tid = threadIdx.x;

  if (blockIdx.x < NROWS) {
    const size_t row = blockIdx.x;
    const int th = tid >> 4, tl = tid & 15;
    float v[16];
    const float4* src = (const float4*)(in + row * DIN);
    #pragma unroll
    for (int k = 0; k < 4; ++k) {
      float4 f = src[tid * 4 + k];
      v[4 * k + 0] = f.x; v[4 * k + 1] = f.y;
      v[4 * k + 2] = f.z; v[4 * k + 3] = f.w;
    }
    #pragma unroll
    for (int hb = 1; hb < 16; hb <<= 1)
      #pragma unroll
      for (int j = 0; j < 16; ++j)
        if (!(j & hb)) {
          float a0 = v[j], b0 = v[j | hb];
          v[j] = a0 + b0; v[j | hb] = a0 - b0;
        }
    #pragma unroll
    for (int j = 0; j < 16; ++j) lds[17 * tid + j] = v[j];
    __syncthreads();
    #pragma unroll
    for (int j = 0; j < 16; ++j) v[j] = lds[272 * th + 17 * j + tl];
    #pragma unroll
    for (int hb = 1; hb < 16; hb <<= 1)
      #pragma unroll
      for (int j = 0; j < 16; ++j)
        if (!(j & hb)) {
          float a0 = v[j], b0 = v[j | hb];
          v[j] = a0 + b0; v[j | hb] = a0 - b0;
        }
    #pragma unroll
    for (int j = 0; j < 16; ++j) lds[272 * th + 17 * j + tl] = v[j];
    __syncthreads();
    #pragma unroll
    for (int j = 0; j < 16; ++j) v[j] = lds[272 * j + 17 * th + tl];
    #pragma unroll
    for (int hb = 1; hb < 16; hb <<= 1)
      #pragma unroll
      for (int j = 0; j < 16; ++j)
        if (!(j & hb)) {
          float a0 = v[j], b0 = v[j | hb];
          v[j] = a0 + b0; v[j | hb] = a0 - b0;
        }
    float m = 0.0f;
    #pragma unroll
    for (int j = 0; j < 16; ++j) m = fmaxf(m, fabsf(v[j]));
    #pragma unroll
    for (int j = 0; j < 16; ++j) lds[272 * j + 17 * th + tl] = v[j];
    float mx = block_absmax(m, red) * 0.015625f;  // 1/sqrt(4096) exact
    float scale = fmaxf(mx / 127.0f, 1e-8f);
    if (tid == 0) sx[row] = scale;
    const float rs = 1.0f / scale;
    char pk[16];
    #pragma unroll
    for (int j = 0; j < 16; ++j) {
      float q = fminf(fmaxf(rintf((lds[17 * tid + j] * 0.015625f) * rs), -127.f),
                      127.f);
      pk[j] = (char)q;
    }
    *(int4*)(qx + row * DIN + (size_t)tid * 16) = *(const int4*)pk;
  } else {
    const size_t row = blockIdx.x - NROWS;
    const float4* src = (const float4*)(w + row * DIN);
    float4* b4 = (float4*)lds;
    float m = 0.0f;
    for (int i = tid; i < DIN / 4; i += 256) {
      float4 v = src[i];
      b4[i] = v;
      m = fmaxf(m, fmaxf(fmaxf(fabsf(v.x), fabsf(v.y)),
                         fmaxf(fabsf(v.z), fabsf(v.w))));
    }
    float mx = block_absmax(m, red);
    float scale = fmaxf(mx / 7.0f, 1e-8f);
    if (tid == 0) sw[row] = scale;
    char* dst = qw + row * DIN;
    const float rs = 1.0f / scale;
    for (int i0 = tid * 4; i0 < DIN; i0 += 1024) {
      char4 pk;
      float q0 = fminf(fmaxf(rintf(lds[i0 + 0] * rs), -7.f), 7.f);
      float q1 = fminf(fmaxf(rintf(lds[i0 + 1] * rs), -7.f), 7.f);
      float q2 = fminf(fmaxf(rintf(lds[i0 + 2] * rs), -7.f), 7.f);
      float q3 = fminf(fmaxf(rintf(lds[i0 + 3] * rs), -7.f), 7.f);
      pk.x = (char)q0; pk.y = (char)q1; pk.z = (char)q2; pk.w = (char)q3;
      *(char4*)(dst + i0) = pk;
    }
  }
}

// ---------------- kernel 3: i8 MFMA GEMM, persistent 2-tile, 8-phase -----------
// R4-EXACT phase bodies (proven 147us / 0 conflicts). 256 blocks; each block
// runs TWO row-adjacent 256x256 tiles (rowA + {0,256}, same col0) as ONE
// seamless 32-iteration K-loop: staging is absolute-kt (kt>=32 -> +256 rows),
// so the pipeline never drains at the tile boundary. Tile0's epilogue (pure
// VMEM/VALU) executes at iter 16 while tile1's staged loads are in flight;
// vmcnt(0) afterwards keeps the counted-vmcnt ledger clean of C-stores.
__global__ __launch_bounds__(512, 2) void gemm_kernel(
    const char* __restrict__ A,   // [NROWS][DIN] q_x int8
    const char* __restrict__ Bt,  // [DOUT][DIN]  q_w int8
    const float* __restrict__ sx, const float* __restrict__ sw,
    const float* __restrict__ bias, float* __restrict__ out) {
  __shared__ char lds[131072];
  const int tid = threadIdx.x;
  const int lane = tid & 63;
  const int wid = tid >> 6;
  const int wr = wid >> 2;  // 0..1
  const int wc = wid & 3;   // 0..3
  int bid = blockIdx.x;                    // 256 blocks
  int swz = (bid & 7) * 32 + (bid >> 3);   // bijective XCD swizzle (256%8==0)
  const size_t rowA = (size_t)(swz >> 4) * 512;  // row-pair base (2 tiles)
  const size_t col0 = (size_t)(swz & 15) * 256;
  const int slot0 = (((lane >> 4) ^ (lane & 7)) << 4);  // swizzled 16B slot

  i32x4 acc[4][2][4] = {};  // [slab q][mm][nn] — C^T fragments
  i32x4 fb[4][2];           // [nn][kk]
  i32x4 fa[2][2];           // [mm][kk]

#define STAGE(MAT, GROW0, KT, LBASE)                                          \
  {                                                                           \
    _Pragma("unroll")                                                         \
    for (int j = 0; j < 2; ++j) {                                             \
      int chunk = j * 8 + wid;                                                \
      int rr = chunk * 8 + (lane >> 3);                                       \
      int cc = ((KT) & 31) * 128 + (((lane & 7) ^ (lane >> 3)) << 4);         \
      const char* src = (MAT) + ((GROW0) + rr) * (size_t)DIN + cc;            \
      __builtin_amdgcn_global_load_lds(                                       \
          (const __attribute__((address_space(1))) void*)src,                 \
          (__attribute__((address_space(3))) void*)(lds + (LBASE) +           \
                                                    chunk * 1024),            \
          16, 0, 0);                                                          \
    }                                                                         \
  }
#define STAGE_A(P, HALF, KT)                                                  \
  STAGE(A, rowA + (((KT) >= 32) ? 256 : 0) + (HALF) * 128, KT,                \
        (P) * 32768 + (HALF) * 16384)
#define STAGE_B(P, HALF, KT) \
  STAGE(Bt, col0 + (HALF) * 128, KT, 65536 + (P) * 32768 + (HALF) * 16384)

#define DS_A(Q, P)                                                            \
  {                                                                           \
    _Pragma("unroll")                                                         \
    for (int mm = 0; mm < 2; ++mm) {                                          \
      int ar = (Q) * 64 + wr * 32 + mm * 16 + (lane & 15);                    \
      _Pragma("unroll")                                                       \
      for (int kk = 0; kk < 2; ++kk)                                          \
        fa[mm][kk] =                                                          \
            *(const i32x4*)(lds + (P) * 32768 + ar * 128 + (slot0 ^ (kk * 64))); \
    }                                                                         \
  }
#define DS_B(P)                                                               \
  {                                                                           \
    _Pragma("unroll")                                                         \
    for (int nn = 0; nn < 4; ++nn) {                                          \
      int br = wc * 64 + nn * 16 + (lane & 15);                               \
      _Pragma("unroll")                                                       \
      for (int kk = 0; kk < 2; ++kk)                                          \
        fb[nn][kk] = *(const i32x4*)(lds + 65536 + (P) * 32768 + br * 128 +   \
                                     (slot0 ^ (kk * 64)));                    \
    }                                                                         \
  }
#define MFMA16(Q)                                                             \
  {                                                                           \
    __builtin_amdgcn_s_setprio(1);                                            \
    _Pragma("unroll")                                                         \
    for (int kk = 0; kk < 2; ++kk)                                            \
      _Pragma("unroll")                                                       \
      for (int mm = 0; mm < 2; ++mm)                                          \
        _Pragma("unroll")                                                     \
        for (int nn = 0; nn < 4; ++nn)                                        \
          acc[Q][mm][nn] = __builtin_amdgcn_mfma_i32_16x16x64_i8(             \
              fb[nn][kk], fa[mm][kk], acc[Q][mm][nn], 0, 0, 0);               \
    __builtin_amdgcn_s_setprio(0);                                            \
  }
#define BAR() __builtin_amdgcn_s_barrier()
#define WAIT_LGKM0() asm volatile("s_waitcnt lgkmcnt(0)" ::: "memory")

// epilogue for tile T (C^T frags, R4-verified): float4 stores, no LDS/barriers
#define EPI(T)                                                                \
  {                                                                           \
    _Pragma("unroll")                                                         \
    for (int q = 0; q < 4; ++q) {                                             \
      _Pragma("unroll")                                                       \
      for (int mm = 0; mm < 2; ++mm) {                                        \
        size_t gr = rowA + (T) * 256 + q * 64 + wr * 32 + mm * 16 + (lane & 15); \
        float sxr = sx[gr];                                                   \
        float* orow = out + gr * DOUT;                                        \
        _Pragma("unroll")                                                     \
        for (int nn = 0; nn < 4; ++nn) {                                      \
          size_t gc0 = col0 + wc * 64 + nn * 16 + ((lane >> 4) << 2);         \
          float4 swv = *(const float4*)(sw + gc0);                            \
          float4 bv = *(const float4*)(bias + gc0);                           \
          float4 o;                                                           \
          o.x = (float)acc[q][mm][nn][0] * (sxr * swv.x) + bv.x;              \
          o.y = (float)acc[q][mm][nn][1] * (sxr * swv.y) + bv.y;              \
          o.z = (float)acc[q][mm][nn][2] * (sxr * swv.z) + bv.z;              \
          o.w = (float)acc[q][mm][nn][3] * (sxr * swv.w) + bv.w;              \
          *(float4*)(orow + gc0) = o;                                         \
        }                                                                     \
      }                                                                       \
    }                                                                         \
  }

  // -------- prologue: kt0 -> buf0 (4 half-tiles), kt1 -> buf1 (3 half-tiles)
  STAGE_B(0, 0, 0); STAGE_B(0, 1, 0); STAGE_A(0, 0, 0); STAGE_A(0, 1, 0);
  STAGE_B(1, 0, 1); STAGE_B(1, 1, 1); STAGE_A(1, 0, 1);
  asm volatile("s_waitcnt vmcnt(6)" ::: "memory");  // buf0 fully landed
  BAR();

  #pragma unroll 1
  for (int i = 0; i < 32; ++i) {
    const int a = 2 * i, b = 2 * i + 1;
    const bool nl = (i < 31);
    // ---- tile boundary: dump tile0 while tile1's staged loads are in flight
    if (i == 16) {
      EPI(0);
      #pragma unroll
      for (int q = 0; q < 4; ++q)
        #pragma unroll
        for (int mm = 0; mm < 2; ++mm)
          #pragma unroll
          for (int nn = 0; nn < 4; ++nn)
            acc[q][mm][nn] = (i32x4){0, 0, 0, 0};
      asm volatile("s_waitcnt vmcnt(0)" ::: "memory");  // clean vmcnt ledger
    }
    // ---- ph1: slab0 of buf0; stage A11 <- kt b (completes buf1)
    DS_A(0, 0); DS_B(0);
    STAGE_A(1, 1, b);
    asm volatile("s_waitcnt lgkmcnt(8)" ::: "memory");
    BAR(); WAIT_LGKM0();
    MFMA16(0);
    BAR();
    // ---- ph2: slab1 of buf0; stage B00 <- kt a+2
    DS_A(1, 0);
    if (nl) STAGE_B(0, 0, a + 2);
    BAR(); WAIT_LGKM0();
    MFMA16(1);
    BAR();
    // ---- ph3: slab2; stage B01
    DS_A(2, 0);
    if (nl) STAGE_B(0, 1, a + 2);
    BAR(); WAIT_LGKM0();
    MFMA16(2);
    BAR();
    // ---- ph4: slab3; stage A00; vmcnt -> buf1 ready
    DS_A(3, 0);
    if (nl) STAGE_A(0, 0, a + 2);
    BAR(); WAIT_LGKM0();
    MFMA16(3);
    if (nl) { asm volatile("s_waitcnt vmcnt(6)" ::: "memory"); }
    else    { asm volatile("s_waitcnt vmcnt(0)" ::: "memory"); }
    BAR();
    // ---- ph5: slab0 of buf1; stage A01
    DS_A(0, 1); DS_B(1);
    if (nl) STAGE_A(0, 1, a + 2);
    asm volatile("s_waitcnt lgkmcnt(8)" ::: "memory");
    BAR(); WAIT_LGKM0();
    MFMA16(0);
    BAR();
    // ---- ph6: slab1 of buf1; stage B10 <- kt b+2
    DS_A(1, 1);
    if (nl) STAGE_B(1, 0, b + 2);
    BAR(); WAIT_LGKM0();
    MFMA16(1);
    BAR();
    // ---- ph7: slab2; stage B11
    DS_A(2, 1);
    if (nl) STAGE_B(1, 1, b + 2);
    BAR(); WAIT_LGKM0();
    MFMA16(2);
    BAR();
    // ---- ph8: slab3; stage A10; vmcnt -> buf0 ready for next iter
    DS_A(3, 1);
    if (nl) STAGE_A(1, 0, b + 2);
    BAR(); WAIT_LGKM0();
    MFMA16(3);
    if (nl) { asm volatile("s_waitcnt vmcnt(6)" ::: "memory"); }
    BAR();
  }

  EPI(1);
#undef STAGE
#undef STAGE_A
#undef STAGE_B
#undef DS_A
#undef DS_B
#undef MFMA16
#undef BAR
#undef WAIT_LGKM0
#undef EPI
}

// ---------------- kernel 4: per-token 8-bit fake quant of output, in place ----
__global__ __launch_bounds__(256) void rowquant_kernel(float* __restrict__ out) {
  __shared__ float red[4];
  const int tid = threadIdx.x;
  const size_t row = blockIdx.x;
  float4* g4 = (float4*)(out + row * DOUT);
  float4 v[4];
  float m = 0.0f;
  #pragma unroll
  for (int k = 0; k < 4; ++k) {
    v[k] = g4[tid + k * 256];
    m = fmaxf(m, fmaxf(fmaxf(fabsf(v[k].x), fabsf(v[k].y)),
                       fmaxf(fabsf(v[k].z), fabsf(v[k].w))));
  }
  float mx = block_absmax(m, red);
  float scale = fmaxf(mx / 127.0f, 1e-8f);
  #pragma unroll
  for (int k = 0; k < 4; ++k) {
    float4 w = v[k];
    w.x = fminf(fmaxf(rintf(w.x / scale), -127.0f), 127.0f) * scale;
    w.y = fminf(fmaxf(rintf(w.y / scale), -127.0f), 127.0f) * scale;
    w.z = fminf(fmaxf(rintf(w.z / scale), -127.0f), 127.0f) * scale;
    w.w = fminf(fmaxf(rintf(w.w / scale), -127.0f), 127.0f) * scale;
    g4[tid + k * 256] = w;
  }
}

extern "C" void kernel_launch(void* const* d_in, const int* in_sizes, int n_in,
                              void* d_out, int out_size, void* d_ws, size_t ws_size,
                              hipStream_t stream) {
  (void)in_sizes; (void)n_in; (void)out_size; (void)ws_size;
  const float* input = (const float*)d_in[0];
  const float* weight = (const float*)d_in[1];
  const float* bias = (const float*)d_in[2];
  float* out = (float*)d_out;
  char* ws = (char*)d_ws;
  char* qx = ws;
  char* qw = ws + ((size_t)32 << 20);
  float* sx = (float*)(ws + ((size_t)48 << 20));
  float* sw = (float*)(ws + ((size_t)48 << 20) + ((size_t)32 << 10));

  fused_quant_kernel<<<NROWS + DOUT, 256, 0, stream>>>(input, weight, qx, qw,
                                                       sx, sw);
  gemm_kernel<<<256, 512, 0, stream>>>(qx, qw, sx, sw, bias, out);
  rowquant_kernel<<<NROWS, 256, 0, stream>>>(out);
}